// Round 1
// baseline (1301.530 us; speedup 1.0000x reference)
//
#include <hip/hip_runtime.h>
#include <hip/hip_bf16.h>

typedef __bf16 bf16x8 __attribute__((ext_vector_type(8)));
typedef __bf16 bf16x4 __attribute__((ext_vector_type(4)));
typedef float  f32x4  __attribute__((ext_vector_type(4)));

static constexpr int BB   = 1024;   // batch
static constexpr int INF  = 256;    // IN
static constexpr int LATF = 512;    // LAT
static constexpr int HIDF = 1024;   // HID
static constexpr int OUTF = 64;     // OUT
static constexpr float DT = 0.05f;  // (T1-T0)/N_STEPS

// ---------------- fp32 -> bf16 elementwise (n4 = n/4) ----------------
__global__ void conv_bf16_k(const float* __restrict__ in, __bf16* __restrict__ out, int n4) {
    int i = blockIdx.x * blockDim.x + threadIdx.x;
    if (i < n4) {
        float4 v = reinterpret_cast<const float4*>(in)[i];
        bf16x4 o;
        o[0] = (__bf16)v.x; o[1] = (__bf16)v.y; o[2] = (__bf16)v.z; o[3] = (__bf16)v.w;
        reinterpret_cast<bf16x4*>(out)[i] = o;
    }
}

// ---------------- transpose fp32[R][C] -> bf16[C][R] ----------------
// grid (C/32, R/32), block (32, 8). R, C multiples of 32.
__global__ void transpose_bf16_k(const float* __restrict__ in, __bf16* __restrict__ out,
                                 int R, int C) {
    __shared__ float tile[32][33];
    const int c0 = blockIdx.x * 32, r0 = blockIdx.y * 32;
    const int tx = threadIdx.x, ty = threadIdx.y;
#pragma unroll
    for (int i = 0; i < 32; i += 8)
        tile[ty + i][tx] = in[(size_t)(r0 + ty + i) * C + (c0 + tx)];
    __syncthreads();
#pragma unroll
    for (int i = 0; i < 32; i += 8)
        out[(size_t)(c0 + ty + i) * R + (r0 + tx)] = (__bf16)tile[tx][ty + i];
}

// ---------------- fused GEMM: C = A(bf16, MxK) @ Bt(bf16, NxK)^T ----------------
// TM=64 rows per block, TN columns per block (64 or 32). 256 threads = 4 waves (2x2).
// MODE 0: h0    : v = tanh(acc + bias[col]);           h=v, zb=bf16(v)        (N=LAT)
// MODE 1: dynG1 : v = tanh(acc + bias[col]+t*wl[col]); gb=bf16(v)             (N=HID)
// MODE 2: dynG2 : kv = acc + bias[col]; kout=kv; zb=bf16(h + coef*kv)         (N=LAT)
// MODE 3: dynG2k4: kv=acc+bias; h += DT/6*(k1+2k2+2k3+kv); zb=bf16(h)         (N=LAT)
template <int TN, int MODE>
__global__ __launch_bounds__(256)
void gemm_k(const __bf16* __restrict__ A, const __bf16* __restrict__ Bt, const int K,
            float* __restrict__ hbuf, __bf16* __restrict__ zb, __bf16* __restrict__ gb,
            float* __restrict__ kout, const float* __restrict__ kb1,
            const float* __restrict__ kb2, const float* __restrict__ kb3,
            const float* __restrict__ bias, const float* __restrict__ wlast,
            const float tval, const float coef) {
    constexpr int FN = TN / 32;  // 2 (TN=64) or 1 (TN=32)
    __shared__ __align__(16) __bf16 As[2][64][32];
    __shared__ __align__(16) __bf16 Bs[2][TN][32];

    const int tid  = threadIdx.x;
    const int lane = tid & 63;
    const int wv   = tid >> 6;
    const int wr   = wv >> 1, wc = wv & 1;
    const int m0   = blockIdx.x * 64;
    const int n0   = blockIdx.y * TN;

    // staging: each thread loads one 16B chunk per tile
    const int ar = tid >> 2, ak = (tid & 3) << 3;          // A: 64 rows x 32k
    const bool bact = (TN == 64) || (tid < 128);
    const int br = (tid & (TN * 4 - 1)) >> 2;              // B: TN rows x 32k

    const __bf16* Arow = A  + (size_t)(m0 + ar) * K + ak;
    const __bf16* Brow = Bt + (size_t)(n0 + br) * K + ak;

    const int KT = K >> 5;

    bf16x8 ra, rb;
    ra = *reinterpret_cast<const bf16x8*>(Arow);
    if (bact) rb = *reinterpret_cast<const bf16x8*>(Brow);
    *reinterpret_cast<bf16x8*>(&As[0][ar][ak]) = ra;
    if (bact) *reinterpret_cast<bf16x8*>(&Bs[0][br][ak]) = rb;
    if (KT > 1) {
        ra = *reinterpret_cast<const bf16x8*>(Arow + 32);
        if (bact) rb = *reinterpret_cast<const bf16x8*>(Brow + 32);
    }
    __syncthreads();

    f32x4 acc[2][FN];
#pragma unroll
    for (int mi = 0; mi < 2; ++mi)
#pragma unroll
        for (int ni = 0; ni < FN; ++ni) acc[mi][ni] = f32x4{0.f, 0.f, 0.f, 0.f};

    const int arow0 = wr * 32 + (lane & 15);
    const int bcol0 = wc * (TN / 2) + (lane & 15);
    const int kk    = (lane >> 4) << 3;

    for (int kt = 0; kt < KT; ++kt) {
        const int cur = kt & 1;
        if (kt + 1 < KT) {
            // write next buffer from regs (loaded 1-2 iters ago), then issue kt+2 loads
            *reinterpret_cast<bf16x8*>(&As[cur ^ 1][ar][ak]) = ra;
            if (bact) *reinterpret_cast<bf16x8*>(&Bs[cur ^ 1][br][ak]) = rb;
            if (kt + 2 < KT) {
                ra = *reinterpret_cast<const bf16x8*>(Arow + (size_t)(kt + 2) * 32);
                if (bact) rb = *reinterpret_cast<const bf16x8*>(Brow + (size_t)(kt + 2) * 32);
            }
        }
        // compute on cur
        bf16x8 af[2], bfr[FN];
#pragma unroll
        for (int mi = 0; mi < 2; ++mi)
            af[mi] = *reinterpret_cast<const bf16x8*>(&As[cur][arow0 + mi * 16][kk]);
#pragma unroll
        for (int ni = 0; ni < FN; ++ni)
            bfr[ni] = *reinterpret_cast<const bf16x8*>(&Bs[cur][bcol0 + ni * 16][kk]);
#pragma unroll
        for (int mi = 0; mi < 2; ++mi)
#pragma unroll
            for (int ni = 0; ni < FN; ++ni)
                acc[mi][ni] = __builtin_amdgcn_mfma_f32_16x16x32_bf16(af[mi], bfr[ni],
                                                                      acc[mi][ni], 0, 0, 0);
        __syncthreads();
    }

    // epilogue. D mapping (m89-verified): col = lane&15, row = (lane>>4)*4 + j
    const int lr = (lane >> 4) << 2;
    const int lc = lane & 15;
#pragma unroll
    for (int mi = 0; mi < 2; ++mi) {
#pragma unroll
        for (int ni = 0; ni < FN; ++ni) {
#pragma unroll
            for (int j = 0; j < 4; ++j) {
                const int row = m0 + wr * 32 + mi * 16 + lr + j;
                const int col = n0 + wc * (TN / 2) + ni * 16 + lc;
                const float a = acc[mi][ni][j];
                if (MODE == 0) {
                    const float v  = tanhf(a + bias[col]);
                    const int idx  = row * LATF + col;
                    hbuf[idx] = v;
                    zb[idx]   = (__bf16)v;
                } else if (MODE == 1) {
                    const float v = tanhf(a + bias[col] + tval * wlast[col]);
                    gb[row * HIDF + col] = (__bf16)v;
                } else if (MODE == 2) {
                    const int idx  = row * LATF + col;
                    const float kv = a + bias[col];
                    kout[idx] = kv;
                    zb[idx]   = (__bf16)(hbuf[idx] + coef * kv);
                } else {
                    const int idx  = row * LATF + col;
                    const float kv = a + bias[col];
                    const float hn = hbuf[idx] + (DT / 6.0f) *
                                     (kb1[idx] + 2.0f * kb2[idx] + 2.0f * kb3[idx] + kv);
                    hbuf[idx] = hn;
                    zb[idx]   = (__bf16)hn;
                }
            }
        }
    }
}

// ---------------- out = h[:, :256] @ W_out + b_out (fp32) ----------------
// grid BB/16, block 256. thread: col = tid&63, row group = tid>>6 (4 rows each)
__global__ __launch_bounds__(256)
void out_k(const float* __restrict__ h, const float* __restrict__ Wout,
           const float* __restrict__ bout, float* __restrict__ out) {
    const int col = threadIdx.x & 63;
    const int rg  = threadIdx.x >> 6;
    const int r0  = blockIdx.x * 16 + rg * 4;
    float a0 = 0.f, a1 = 0.f, a2 = 0.f, a3 = 0.f;
    for (int k = 0; k < INF; ++k) {
        const float w = Wout[k * OUTF + col];
        a0 += h[(r0 + 0) * LATF + k] * w;
        a1 += h[(r0 + 1) * LATF + k] * w;
        a2 += h[(r0 + 2) * LATF + k] * w;
        a3 += h[(r0 + 3) * LATF + k] * w;
    }
    const float b = bout[col];
    out[(r0 + 0) * OUTF + col] = a0 + b;
    out[(r0 + 1) * OUTF + col] = a1 + b;
    out[(r0 + 2) * OUTF + col] = a2 + b;
    out[(r0 + 3) * OUTF + col] = a3 + b;
}

extern "C" void kernel_launch(void* const* d_in, const int* in_sizes, int n_in,
                              void* d_out, int out_size, void* d_ws, size_t ws_size,
                              hipStream_t stream) {
    const float* x     = (const float*)d_in[0];
    const float* W_in  = (const float*)d_in[1];
    const float* b_in  = (const float*)d_in[2];
    const float* W1    = (const float*)d_in[3];   // (LAT+1, HID)
    const float* b1    = (const float*)d_in[4];
    const float* W2    = (const float*)d_in[5];   // (HID, LAT)
    const float* b2    = (const float*)d_in[6];
    const float* W_out = (const float*)d_in[7];   // (LAT/2, OUT)
    const float* b_out = (const float*)d_in[8];
    float* out = (float*)d_out;

    char* ws = (char*)d_ws;
    size_t off = 0;
    auto alloc = [&](size_t bytes) {
        void* p = ws + off;
        off += (bytes + 255) & ~(size_t)255;
        return p;
    };
    __bf16* xb   = (__bf16*)alloc((size_t)BB * INF * 2);
    __bf16* WinT = (__bf16*)alloc((size_t)LATF * INF * 2);   // [LAT][IN]
    __bf16* W1T  = (__bf16*)alloc((size_t)HIDF * LATF * 2);  // [HID][LAT]
    __bf16* W2T  = (__bf16*)alloc((size_t)LATF * HIDF * 2);  // [LAT][HID]
    float*  h    = (float*)alloc((size_t)BB * LATF * 4);
    __bf16* zbuf = (__bf16*)alloc((size_t)BB * LATF * 2);
    __bf16* gbuf = (__bf16*)alloc((size_t)BB * HIDF * 2);
    float*  k1   = (float*)alloc((size_t)BB * LATF * 4);
    float*  k2   = (float*)alloc((size_t)BB * LATF * 4);
    float*  k3   = (float*)alloc((size_t)BB * LATF * 4);
    if (off > ws_size) return;  // workspace too small: leave output zeroed (diagnostic)

    // weight/input prep (once per launch; cheap, deterministic)
    conv_bf16_k<<<(BB * INF / 4 + 255) / 256, 256, 0, stream>>>(x, xb, BB * INF / 4);
    transpose_bf16_k<<<dim3(LATF / 32, INF / 32), dim3(32, 8), 0, stream>>>(W_in, WinT, INF, LATF);
    transpose_bf16_k<<<dim3(HIDF / 32, LATF / 32), dim3(32, 8), 0, stream>>>(W1, W1T, LATF, HIDF);
    transpose_bf16_k<<<dim3(LATF / 32, HIDF / 32), dim3(32, 8), 0, stream>>>(W2, W2T, HIDF, LATF);

    const float* w1last = W1 + (size_t)LATF * HIDF;  // row 512 of W1 (t coefficients)

    // h0 = tanh(x @ W_in + b_in)
    gemm_k<64, 0><<<dim3(BB / 64, LATF / 64), 256, 0, stream>>>(
        xb, WinT, INF, h, zbuf, nullptr, nullptr, nullptr, nullptr, nullptr,
        b_in, nullptr, 0.f, 0.f);

    for (int s = 0; s < 20; ++s) {
        const float t0 = DT * (float)s;
        const float th = t0 + 0.5f * DT;
        const float t1 = t0 + DT;
        // k1
        gemm_k<64, 1><<<dim3(BB / 64, HIDF / 64), 256, 0, stream>>>(
            zbuf, W1T, LATF, nullptr, nullptr, gbuf, nullptr, nullptr, nullptr, nullptr,
            b1, w1last, t0, 0.f);
        gemm_k<32, 2><<<dim3(BB / 64, LATF / 32), 256, 0, stream>>>(
            gbuf, W2T, HIDF, h, zbuf, nullptr, k1, nullptr, nullptr, nullptr,
            b2, nullptr, 0.f, 0.5f * DT);
        // k2
        gemm_k<64, 1><<<dim3(BB / 64, HIDF / 64), 256, 0, stream>>>(
            zbuf, W1T, LATF, nullptr, nullptr, gbuf, nullptr, nullptr, nullptr, nullptr,
            b1, w1last, th, 0.f);
        gemm_k<32, 2><<<dim3(BB / 64, LATF / 32), 256, 0, stream>>>(
            gbuf, W2T, HIDF, h, zbuf, nullptr, k2, nullptr, nullptr, nullptr,
            b2, nullptr, 0.f, 0.5f * DT);
        // k3
        gemm_k<64, 1><<<dim3(BB / 64, HIDF / 64), 256, 0, stream>>>(
            zbuf, W1T, LATF, nullptr, nullptr, gbuf, nullptr, nullptr, nullptr, nullptr,
            b1, w1last, th, 0.f);
        gemm_k<32, 2><<<dim3(BB / 64, LATF / 32), 256, 0, stream>>>(
            gbuf, W2T, HIDF, h, zbuf, nullptr, k3, nullptr, nullptr, nullptr,
            b2, nullptr, 0.f, DT);
        // k4 + state update
        gemm_k<64, 1><<<dim3(BB / 64, HIDF / 64), 256, 0, stream>>>(
            zbuf, W1T, LATF, nullptr, nullptr, gbuf, nullptr, nullptr, nullptr, nullptr,
            b1, w1last, t1, 0.f);
        gemm_k<32, 3><<<dim3(BB / 64, LATF / 32), 256, 0, stream>>>(
            gbuf, W2T, HIDF, h, zbuf, nullptr, nullptr, k1, k2, k3,
            b2, nullptr, 0.f, 0.f);
    }

    out_k<<<BB / 16, 256, 0, stream>>>(h, W_out, b_out, out);
}